// Round 2
// baseline (2153.814 us; speedup 1.0000x reference)
//
#include <hip/hip_runtime.h>
#include <math.h>

// ---------------------------------------------------------------------------
// ws layout (float offsets), total exactly 96 MiB (proven available in R1):
//   rep3  [0       .. 196608)   conv3 weights repacked [128][128][12]
//   repr1 [196608  .. 245760)   r1w1 repacked [32][128][12]
//   repr2 [245760  .. 294912)   r2w1 repacked
//   tbuf  [294912  .. 2392064)  res3 output [16,32,64,64]
//   R0    [8388608 .. 16777216) conv1 half-out [8,64,128,128] -> later h [16,128,64,64]
//   R2    [16777216.. 25165824) conv2 out [16,128,64,64]
// Schedule: repacks; conv1(n<8)->R0; conv2(n<8)->R2; conv1(n>=8)->R0;
//           conv2(n>=8)->R2; conv3(R2)->R0; 2x(res3->tbuf; res1x1 tbuf->R0+=);
//           prevq(R0)->out.
// ---------------------------------------------------------------------------

#define REP3  0
#define REPR1 196608
#define REPR2 245760
#define TBUF  294912
#define R0OFF 8388608
#define R2OFF 16777216

// pad 3x3 weights 9 -> 12 floats so per-(oc,ic) chunks are 16B-aligned
__global__ __launch_bounds__(256) void repack_k(
    const float* __restrict__ src, float* __restrict__ dst, int count)
{
    int i = blockIdx.x * 256 + threadIdx.x;
    if (i >= count) return;
#pragma unroll
    for (int k = 0; k < 9; k++) dst[i * 12 + k] = src[i * 9 + k];
    dst[i * 12 + 9] = 0.f; dst[i * 12 + 10] = 0.f; dst[i * 12 + 11] = 0.f;
}

// conv1: [8,1,256,256] -> [8,64,128,128], 4x4 s2 p1, relu. (half batch)
// lane=ox(64 of 128, xh picks half), wave=16-oc subgroup, 2 oy/thread.
__global__ __launch_bounds__(256) void conv1_k(
    const float* __restrict__ x, const float* __restrict__ w,
    const float* __restrict__ b, float* __restrict__ out)
{
    int lane = threadIdx.x & 63, wv = threadIdx.x >> 6;
    int bx = blockIdx.x;
    int n = bx >> 7, rem = bx & 127;     // 8 n * (64 ytiles * 2 xh)
    int ytile = rem >> 1, xh = rem & 1;
    int ox = xh * 64 + lane;
    int oy0 = ytile * 2;
    int r0 = 4 * ytile - 1;
    const float* xb = x + n * 65536;
    float v[6][4];
#pragma unroll
    for (int r = 0; r < 6; r++) {
        int iy = r0 + r;
        bool rv = (iy >= 0) && (iy < 256);
        const float* pr = xb + iy * 256 + 2 * ox - 1;
        bool cv0 = (ox > 0);
#pragma unroll
        for (int c = 0; c < 4; c++) {
            bool cv = (c == 0) ? cv0 : ((c == 3) ? (2 * ox + 2 < 256) : true);
            v[r][c] = (rv && cv) ? pr[c] : 0.f;
        }
    }
    int ocb = wv * 16;
    float acc[2][16];
#pragma unroll
    for (int j = 0; j < 16; j++) { float bj = b[ocb + j]; acc[0][j] = bj; acc[1][j] = bj; }
#pragma unroll
    for (int j = 0; j < 16; j++) {
        const float4* wp = (const float4*)(w + (ocb + j) * 16);
        float4 a0 = wp[0], a1 = wp[1], a2 = wp[2], a3 = wp[3];
        float wk[16] = {a0.x,a0.y,a0.z,a0.w, a1.x,a1.y,a1.z,a1.w,
                        a2.x,a2.y,a2.z,a2.w, a3.x,a3.y,a3.z,a3.w};
#pragma unroll
        for (int p = 0; p < 2; p++)
#pragma unroll
        for (int ky = 0; ky < 4; ky++)
#pragma unroll
        for (int kx = 0; kx < 4; kx++)
            acc[p][j] = fmaf(v[2 * p + ky][kx], wk[ky * 4 + kx], acc[p][j]);
    }
#pragma unroll
    for (int j = 0; j < 16; j++)
#pragma unroll
    for (int p = 0; p < 2; p++)
        out[(n * 64 + ocb + j) * 16384 + (oy0 + p) * 128 + ox] = fmaxf(acc[p][j], 0.f);
}

// conv2: [8,64,128,128] -> [8(+n0),128,64,64], 4x4 s2 p1, relu.
// lane=ox, wave=8-oc subgroup (block: 32 oc via blockIdx.y), 2 oy/thread.
__global__ __launch_bounds__(256) void conv2_k(
    const float* __restrict__ in, const float* __restrict__ w,
    const float* __restrict__ b, float* __restrict__ out, int n0)
{
    int lane = threadIdx.x & 63, wv = threadIdx.x >> 6;
    int bx = blockIdx.x;
    int n = bx >> 5, ytile = bx & 31;
    int ocb = blockIdx.y * 32 + wv * 8;
    int ox = lane;
    int oy0 = ytile * 2;
    int r0 = 4 * ytile - 1;
    const float* inb = in + n * 64 * 16384;
    bool cv0 = (ox > 0), cv3 = (ox < 63);
    float acc[2][8];
#pragma unroll
    for (int j = 0; j < 8; j++) { float bj = b[ocb + j]; acc[0][j] = bj; acc[1][j] = bj; }
    for (int ic = 0; ic < 64; ic++) {
        const float* p = inb + ic * 16384;
        float v[6][4];
#pragma unroll
        for (int r = 0; r < 6; r++) {
            int iy = r0 + r;
            bool rv = (iy >= 0) && (iy < 128);
            const float* pr = p + iy * 128 + 2 * ox - 1;
            v[r][0] = (rv && cv0) ? pr[0] : 0.f;
            v[r][1] = rv ? pr[1] : 0.f;
            v[r][2] = rv ? pr[2] : 0.f;
            v[r][3] = (rv && cv3) ? pr[3] : 0.f;
        }
#pragma unroll
        for (int j = 0; j < 8; j++) {
            const float4* wp = (const float4*)(w + ((ocb + j) * 64 + ic) * 16);
            float4 a0 = wp[0], a1 = wp[1], a2 = wp[2], a3 = wp[3];
            float wk[16] = {a0.x,a0.y,a0.z,a0.w, a1.x,a1.y,a1.z,a1.w,
                            a2.x,a2.y,a2.z,a2.w, a3.x,a3.y,a3.z,a3.w};
#pragma unroll
            for (int p2 = 0; p2 < 2; p2++)
#pragma unroll
            for (int ky = 0; ky < 4; ky++)
#pragma unroll
            for (int kx = 0; kx < 4; kx++)
                acc[p2][j] = fmaf(v[2 * p2 + ky][kx], wk[ky * 4 + kx], acc[p2][j]);
        }
    }
#pragma unroll
    for (int j = 0; j < 8; j++)
#pragma unroll
    for (int p2 = 0; p2 < 2; p2++)
        out[((n0 + n) * 128 + ocb + j) * 4096 + (oy0 + p2) * 64 + ox] = fmaxf(acc[p2][j], 0.f);
}

// conv3: [16,128,64,64] -> [16,128,64,64], 3x3 p1, no relu. Repacked weights.
// lane=ox, wave=8-oc subgroup, 4 oy/thread.
__global__ __launch_bounds__(256) void conv3_k(
    const float* __restrict__ in, const float* __restrict__ wr,
    const float* __restrict__ b, float* __restrict__ out)
{
    int lane = threadIdx.x & 63, wv = threadIdx.x >> 6;
    int bx = blockIdx.x;
    int n = bx >> 4, ytile = bx & 15;
    int ocb = blockIdx.y * 32 + wv * 8;
    int ox = lane;
    int oy0 = ytile * 4;
    int r0 = oy0 - 1;
    const float* inb = in + n * 128 * 4096;
    bool cv0 = (ox > 0), cv2 = (ox < 63);
    float acc[4][8];
#pragma unroll
    for (int j = 0; j < 8; j++) {
        float bj = b[ocb + j];
#pragma unroll
        for (int p = 0; p < 4; p++) acc[p][j] = bj;
    }
    for (int ic = 0; ic < 128; ic++) {
        const float* p = inb + ic * 4096;
        float v[6][3];
#pragma unroll
        for (int r = 0; r < 6; r++) {
            int iy = r0 + r;
            bool rv = (iy >= 0) && (iy < 64);
            const float* pr = p + iy * 64 + ox - 1;
            v[r][0] = (rv && cv0) ? pr[0] : 0.f;
            v[r][1] = rv ? pr[1] : 0.f;
            v[r][2] = (rv && cv2) ? pr[2] : 0.f;
        }
#pragma unroll
        for (int j = 0; j < 8; j++) {
            const float* wp = wr + ((ocb + j) * 128 + ic) * 12;
            float4 a0 = *(const float4*)wp;
            float4 a1 = *(const float4*)(wp + 4);
            float w8 = wp[8];
            float wk[9] = {a0.x,a0.y,a0.z,a0.w, a1.x,a1.y,a1.z,a1.w, w8};
#pragma unroll
            for (int p2 = 0; p2 < 4; p2++)
#pragma unroll
            for (int ky = 0; ky < 3; ky++)
#pragma unroll
            for (int kx = 0; kx < 3; kx++)
                acc[p2][j] = fmaf(v[p2 + ky][kx], wk[ky * 3 + kx], acc[p2][j]);
        }
    }
#pragma unroll
    for (int j = 0; j < 8; j++)
#pragma unroll
    for (int p2 = 0; p2 < 4; p2++)
        out[(n * 128 + ocb + j) * 4096 + (oy0 + p2) * 64 + ox] = acc[p2][j];
}

// res3: t = conv3x3(relu(h)) + bias, 128 -> 32 oc. Repacked weights.
// lane=ox, wave=8-oc subgroup (4 waves cover all 32 oc), 2 oy/thread.
__global__ __launch_bounds__(256) void res3_k(
    const float* __restrict__ in, const float* __restrict__ wr,
    const float* __restrict__ b, float* __restrict__ out)
{
    int lane = threadIdx.x & 63, wv = threadIdx.x >> 6;
    int bx = blockIdx.x;
    int n = bx >> 5, ytile = bx & 31;
    int ocb = wv * 8;
    int ox = lane;
    int oy0 = ytile * 2;
    int r0 = oy0 - 1;
    const float* inb = in + n * 128 * 4096;
    bool cv0 = (ox > 0), cv2 = (ox < 63);
    float acc[2][8];
#pragma unroll
    for (int j = 0; j < 8; j++) { float bj = b[ocb + j]; acc[0][j] = bj; acc[1][j] = bj; }
    for (int ic = 0; ic < 128; ic++) {
        const float* p = inb + ic * 4096;
        float v[4][3];
#pragma unroll
        for (int r = 0; r < 4; r++) {
            int iy = r0 + r;
            bool rv = (iy >= 0) && (iy < 64);
            const float* pr = p + iy * 64 + ox - 1;
            v[r][0] = (rv && cv0) ? fmaxf(pr[0], 0.f) : 0.f;
            v[r][1] = rv ? fmaxf(pr[1], 0.f) : 0.f;
            v[r][2] = (rv && cv2) ? fmaxf(pr[2], 0.f) : 0.f;
        }
#pragma unroll
        for (int j = 0; j < 8; j++) {
            const float* wp = wr + ((ocb + j) * 128 + ic) * 12;
            float4 a0 = *(const float4*)wp;
            float4 a1 = *(const float4*)(wp + 4);
            float w8 = wp[8];
            float wk[9] = {a0.x,a0.y,a0.z,a0.w, a1.x,a1.y,a1.z,a1.w, w8};
#pragma unroll
            for (int p2 = 0; p2 < 2; p2++)
#pragma unroll
            for (int ky = 0; ky < 3; ky++)
#pragma unroll
            for (int kx = 0; kx < 3; kx++)
                acc[p2][j] = fmaf(v[p2 + ky][kx], wk[ky * 3 + kx], acc[p2][j]);
        }
    }
#pragma unroll
    for (int j = 0; j < 8; j++)
#pragma unroll
    for (int p2 = 0; p2 < 2; p2++)
        out[(n * 32 + ocb + j) * 4096 + (oy0 + p2) * 64 + ox] = acc[p2][j];
}

// residual 1x1: h += conv1x1(relu(t)) + bias.  t:[16,32,64,64], h:[16,128,64,64]
__global__ __launch_bounds__(256) void res1x1_k(
    const float* __restrict__ t, const float* __restrict__ w,
    const float* __restrict__ b, float* __restrict__ h)
{
    int tid = blockIdx.x * 256 + threadIdx.x;     // 65536
    int n   = tid >> 12;
    int pos = tid & 4095;
    int ocb = blockIdx.y * 32;
    const float* tb = t + n * 32 * 4096 + pos;
    float v[32];
#pragma unroll
    for (int ic = 0; ic < 32; ic++) v[ic] = fmaxf(tb[ic * 4096], 0.f);
    float* hb = h + (n * 128 + ocb) * 4096 + pos;
#pragma unroll
    for (int j = 0; j < 32; j++) {
        float acc = b[ocb + j];
        const float* wj = w + (ocb + j) * 32;
#pragma unroll
        for (int ic = 0; ic < 32; ic++) acc = fmaf(v[ic], wj[ic], acc);
        hb[j * 4096] += acc;
    }
}

// fused: z = conv1x1(relu(h), wpre) + bpre ; cosine-sim VQ ; out = codebook[idx]
__global__ __launch_bounds__(256) void prevq_k(
    const float* __restrict__ h, const float* __restrict__ wpre,
    const float* __restrict__ bpre, const float* __restrict__ cb,
    float* __restrict__ out)
{
    __shared__ float4 en[2048];                   // normalized codebook, 32 KB
    for (int i = threadIdx.x; i < 2048; i += 256) {
        float c0 = cb[i * 4 + 0], c1 = cb[i * 4 + 1];
        float c2 = cb[i * 4 + 2], c3 = cb[i * 4 + 3];
        float nrm = sqrtf(c0 * c0 + c1 * c1 + c2 * c2 + c3 * c3) + 1e-12f;
        en[i] = make_float4(c0 / nrm, c1 / nrm, c2 / nrm, c3 / nrm);
    }
    __syncthreads();

    int tid = blockIdx.x * 256 + threadIdx.x;     // 65536
    int n   = tid >> 12;
    int pos = tid & 4095;
    const float* hb = h + n * 128 * 4096 + pos;
    float z0 = bpre[0], z1 = bpre[1], z2 = bpre[2], z3 = bpre[3];
    for (int ic = 0; ic < 128; ic++) {
        float v = fmaxf(hb[ic * 4096], 0.f);
        z0 = fmaf(v, wpre[ic],       z0);
        z1 = fmaf(v, wpre[128 + ic], z1);
        z2 = fmaf(v, wpre[256 + ic], z2);
        z3 = fmaf(v, wpre[384 + ic], z3);
    }
    float nrm = sqrtf(z0 * z0 + z1 * z1 + z2 * z2 + z3 * z3) + 1e-12f;
    z0 /= nrm; z1 /= nrm; z2 /= nrm; z3 /= nrm;

    float best = -1e30f;
    int   bidx = 0;
    for (int k = 0; k < 2048; k++) {
        float4 e = en[k];
        float s = z0 * e.x + z1 * e.y + z2 * e.z + z3 * e.w;
        if (s > best) { best = s; bidx = k; }     // strict > => first max (jnp.argmax)
    }
    const float* q = cb + bidx * 4;               // raw (un-normalized) code
    out[(n * 4 + 0) * 4096 + pos] = q[0];
    out[(n * 4 + 1) * 4096 + pos] = q[1];
    out[(n * 4 + 2) * 4096 + pos] = q[2];
    out[(n * 4 + 3) * 4096 + pos] = q[3];
}

extern "C" void kernel_launch(void* const* d_in, const int* in_sizes, int n_in,
                              void* d_out, int out_size, void* d_ws, size_t ws_size,
                              hipStream_t stream)
{
    const float* x    = (const float*)d_in[0];
    const float* w1   = (const float*)d_in[1];
    const float* b1   = (const float*)d_in[2];
    const float* w2   = (const float*)d_in[3];
    const float* b2   = (const float*)d_in[4];
    const float* w3   = (const float*)d_in[5];
    const float* b3   = (const float*)d_in[6];
    const float* r1w1 = (const float*)d_in[7];
    const float* r1b1 = (const float*)d_in[8];
    const float* r1w2 = (const float*)d_in[9];
    const float* r1b2 = (const float*)d_in[10];
    const float* r2w1 = (const float*)d_in[11];
    const float* r2b1 = (const float*)d_in[12];
    const float* r2w2 = (const float*)d_in[13];
    const float* r2b2 = (const float*)d_in[14];
    const float* wpre = (const float*)d_in[15];
    const float* bpre = (const float*)d_in[16];
    const float* cb   = (const float*)d_in[17];
    float* out = (float*)d_out;

    float* ws    = (float*)d_ws;
    float* rep3  = ws + REP3;
    float* repr1 = ws + REPR1;
    float* repr2 = ws + REPR2;
    float* tb    = ws + TBUF;
    float* R0    = ws + R0OFF;
    float* R2    = ws + R2OFF;

    // one-time-per-call weight repacks (tiny)
    repack_k<<<64, 256, 0, stream>>>(w3,   rep3,  128 * 128);
    repack_k<<<16, 256, 0, stream>>>(r1w1, repr1, 32 * 128);
    repack_k<<<16, 256, 0, stream>>>(r2w1, repr2, 32 * 128);

    // encoder front end, batch split in halves ping-ponging through R0
    conv1_k<<<1024, 256, 0, stream>>>(x,               w1, b1, R0);
    conv2_k<<<dim3(256, 4), 256, 0, stream>>>(R0, w2, b2, R2, 0);
    conv1_k<<<1024, 256, 0, stream>>>(x + 8 * 65536,   w1, b1, R0);
    conv2_k<<<dim3(256, 4), 256, 0, stream>>>(R0, w2, b2, R2, 8);

    conv3_k<<<dim3(256, 4), 256, 0, stream>>>(R2, rep3, b3, R0);

    // residual block 1
    res3_k  <<<512, 256, 0, stream>>>(R0, repr1, r1b1, tb);
    res1x1_k<<<dim3(256, 4), 256, 0, stream>>>(tb, r1w2, r1b2, R0);
    // residual block 2
    res3_k  <<<512, 256, 0, stream>>>(R0, repr2, r2b1, tb);
    res1x1_k<<<dim3(256, 4), 256, 0, stream>>>(tb, r2w2, r2b2, R0);

    // 1x1 projection + vector quantization
    prevq_k<<<256, 256, 0, stream>>>(R0, wpre, bpre, cb, out);
}

// Round 3
// 798.788 us; speedup vs baseline: 2.6964x; 2.6964x over previous
//
#include <hip/hip_runtime.h>
#include <math.h>

// ---------------------------------------------------------------------------
// ws layout (float offsets), max 20971520 floats = 83.9 MB (< proven 100.7 MB):
//   repW (shorts at base): repW2 @0(393216s), repW3 @393216(442368s),
//                          repR1 @835584(110592s), repR2 @946176(110592s)
//   T  @ 2097152  : t buffer [16,32,64,64]
//   B  @ 4194304  : conv2 out [16,128,64,64]
//   A  @ 12582912 : conv1 half-out [8,64,128,128] -> later h [16,128,64,64]
// ---------------------------------------------------------------------------

typedef short v8s __attribute__((ext_vector_type(8)));
typedef float v4f __attribute__((ext_vector_type(4)));

#define T_OFF 2097152
#define B_OFF 4194304
#define A_OFF 12582912
#define W2_S 0
#define W3_S 393216
#define WR1_S 835584
#define WR2_S 946176

// 3-limb bf16 truncation decomposition: x = h+m+l + O(2^-24 |x|)
__device__ inline void limb3(float v, unsigned short& h, unsigned short& m,
                             unsigned short& l) {
    unsigned ub = __float_as_uint(v);
    unsigned hb = ub & 0xffff0000u;
    float r1 = v - __uint_as_float(hb);
    unsigned mb = __float_as_uint(r1) & 0xffff0000u;
    float r2 = r1 - __uint_as_float(mb);
    unsigned lb = __float_as_uint(r2) & 0xffff0000u;
    h = (unsigned short)(hb >> 16);
    m = (unsigned short)(mb >> 16);
    l = (unsigned short)(lb >> 16);
}

// ----- conv configs ---------------------------------------------------------
struct CfgConv2 {   // 4x4 s2 p1 as stride-1 conv over 4 phase planes
    static constexpr int NC = 8, NT = 4, OC = 128, ICG = 64, IN_H = 128, IN_W = 128;
    static constexpr bool RELU_IN = false, RELU_OUT = true;
    static constexpr int WT_M = 4, WT_N = 2;   // wave: all 4 mtiles, 2 ntiles
    __device__ static void tap(int c, int t, int& ry, int& rx) {
        int py = (c >> 2) & 1, px = (c >> 1) & 1;
        ry = (t >> 1) - py; rx = (t & 1) - px;
    }
    __device__ static void inaddr(int c, int oy, int r, int X,
                                  int& Yg, int& Xg, int& ic0) {
        int py = (c >> 2) & 1, px = (c >> 1) & 1;
        Yg = 2 * (oy + r - 1) + py; Xg = 2 * X + px; ic0 = (c & 1) * 32;
    }
    __device__ static int widx(int c, int t, int oc, int ic) {
        int py = (c >> 2) & 1, px = (c >> 1) & 1, half = c & 1;
        int dy = 2 * (t >> 1) + (1 - py), dx = 2 * (t & 1) + (1 - px);
        return ((oc * 64 + half * 32 + ic) * 4 + dy) * 4 + dx;
    }
};
struct CfgConv3 {   // 3x3 s1 p1, 128->128
    static constexpr int NC = 4, NT = 9, OC = 128, ICG = 128, IN_H = 64, IN_W = 64;
    static constexpr bool RELU_IN = false, RELU_OUT = false;
    static constexpr int WT_M = 4, WT_N = 2;
    __device__ static void tap(int c, int t, int& ry, int& rx) {
        ry = t / 3 - 1; rx = t % 3 - 1;
    }
    __device__ static void inaddr(int c, int oy, int r, int X,
                                  int& Yg, int& Xg, int& ic0) {
        Yg = oy + r - 1; Xg = X; ic0 = c * 32;
    }
    __device__ static int widx(int c, int t, int oc, int ic) {
        return ((oc * 128 + c * 32 + ic) * 3 + t / 3) * 3 + t % 3;
    }
};
struct CfgRes {     // 3x3 s1 p1, relu(in), 128->32
    static constexpr int NC = 4, NT = 9, OC = 32, ICG = 128, IN_H = 64, IN_W = 64;
    static constexpr bool RELU_IN = true, RELU_OUT = false;
    static constexpr int WT_M = 1, WT_N = 2;   // wave w: mtile w, ntiles 0..1
    __device__ static void tap(int c, int t, int& ry, int& rx) {
        ry = t / 3 - 1; rx = t % 3 - 1;
    }
    __device__ static void inaddr(int c, int oy, int r, int X,
                                  int& Yg, int& Xg, int& ic0) {
        Yg = oy + r - 1; Xg = X; ic0 = c * 32;
    }
    __device__ static int widx(int c, int t, int oc, int ic) {
        return ((oc * 128 + c * 32 + ic) * 3 + t / 3) * 3 + t % 3;
    }
};

// ----- weight repack: fp32 -> [(c,t)][limb][oc][32] bf16 limbs --------------
template <typename C>
__global__ __launch_bounds__(256) void repack_k(const float* __restrict__ w,
                                                short* __restrict__ dst) {
    int idx = blockIdx.x * 256 + threadIdx.x;
    int total = C::NC * C::NT * C::OC * 32;
    if (idx >= total) return;
    int s = idx & 31;
    int oc = (idx >> 5) % C::OC;
    int ct = idx / (32 * C::OC);
    int c = ct / C::NT, t = ct % C::NT;
    float val = w[C::widx(c, t, oc, s)];
    unsigned short h, m, l;
    limb3(val, h, m, l);
    int base = ct * 3 * C::OC * 32 + oc * 32 + s;
    dst[base] = (short)h;
    dst[base + C::OC * 32] = (short)m;
    dst[base + 2 * C::OC * 32] = (short)l;
}

// ----- MFMA implicit-GEMM conv (stride-1 formulation) -----------------------
// block = (n_img, oy); M = 64 (x), N = OC. LDS A: 3 limb planes of
// [3 rows][66 cols][32 ic] with rotation swizzle; LDS B: [limb][oc][32].
template <typename C>
__global__ __launch_bounds__(256) void mfma_conv(
    const float* __restrict__ in, const short* __restrict__ repw,
    const float* __restrict__ bias, float* __restrict__ out, int n0)
{
    constexpr int APLANE = 3 * 66 * 32;        // shorts (6336), dwords 3168
    constexpr int BPLANE = C::OC * 32;         // shorts
    __shared__ __align__(16) short lA[3 * APLANE];
    __shared__ __align__(16) short lB[3 * BPLANE];

    int tid = threadIdx.x;
    int lane = tid & 63, wv = tid >> 6;
    int bx = blockIdx.x;
    int n_img = bx >> 6, oy = bx & 63;

    // zero halo cells (col 0 and 65, all rows, all limbs)
    for (int idx = tid; idx < 3 * 3 * 2 * 16; idx += 256) {
        int plane = idx / 96;
        int rem = idx % 96;
        int rr = rem / 32;
        int hc = (rem / 16) & 1;
        int d = idx & 15;
        ((unsigned*)lA)[plane * 3168 + (rr * 66 + hc * 65) * 16 + d] = 0;
    }

    v4f acc[C::WT_M][C::WT_N] = {};
    int mbase = (C::WT_M == 4) ? 0 : wv;
    int nbase = (C::WT_M == 4) ? (wv * C::WT_N) : 0;

    int Xq = tid & 15, icp = tid >> 4;   // staging map: 16 cols x 16 ic-pairs

    for (int c = 0; c < C::NC; c++) {
        __syncthreads();   // prev chunk's readers done before lA overwrite
        // ---- stage A chunk: 3 rows x 64 X x 32 ic, 3 limb planes ----
        for (int it = 0; it < 12; it++) {
            int r = it >> 2, xg = it & 3;
            int X = xg * 16 + Xq;
            int Yg, Xg, ic0;
            C::inaddr(c, oy, r, X, Yg, Xg, ic0);
            float v0 = 0.f, v1 = 0.f;
            if (Yg >= 0 && Yg < C::IN_H) {
                int gbase = ((n_img * C::ICG + ic0 + 2 * icp) * C::IN_H + Yg) * C::IN_W + Xg;
                v0 = in[gbase];
                v1 = in[gbase + C::IN_H * C::IN_W];
            }
            if constexpr (C::RELU_IN) { v0 = fmaxf(v0, 0.f); v1 = fmaxf(v1, 0.f); }
            unsigned short h0, m0, l0, h1, m1, l1;
            limb3(v0, h0, m0, l0);
            limb3(v1, h1, m1, l1);
            int cell = r * 66 + X + 1;
            int rot = (icp + 4 * (cell & 3)) & 15;   // swizzled dword slot
            unsigned* pa = (unsigned*)lA + cell * 16 + rot;
            pa[0]        = (unsigned)h0 | ((unsigned)h1 << 16);
            pa[3168]     = (unsigned)m0 | ((unsigned)m1 << 16);
            pa[2 * 3168] = (unsigned)l0 | ((unsigned)l1 << 16);
        }
        for (int t = 0; t < C::NT; t++) {
            __syncthreads();   // lB readers done (and 1st iter: lA staged)
            // ---- stage B: straight 16B copies of repacked image ----
            {
                const short* src = repw + (c * C::NT + t) * 3 * BPLANE;
                for (int o = tid * 8; o < 3 * BPLANE; o += 2048)
                    *(v8s*)&lB[o] = *(const v8s*)&src[o];
            }
            __syncthreads();
            int ry, rx;
            C::tap(c, t, ry, rx);
            // B fragments (k = quad*8+j -> ic, n = lane&15 -> oc)
            v8s bf[C::WT_N][3];
#pragma unroll
            for (int nt = 0; nt < C::WT_N; nt++) {
                int oc = (nbase + nt) * 16 + (lane & 15);
                int ba = oc * 32 + (lane >> 4) * 8;
#pragma unroll
                for (int L = 0; L < 3; L++)
                    bf[nt][L] = *(const v8s*)&lB[L * BPLANE + ba];
            }
#pragma unroll
            for (int mt = 0; mt < C::WT_M; mt++) {
                int x = (mbase + mt) * 16 + (lane & 15);
                int cell = (ry + 1) * 66 + (x + rx + 1);
                int aa = cell * 32 + (((lane >> 4) + cell) & 3) * 8;
                v8s ah = *(const v8s*)&lA[aa];
                v8s am = *(const v8s*)&lA[APLANE + aa];
                v8s al = *(const v8s*)&lA[2 * APLANE + aa];
#pragma unroll
                for (int nt = 0; nt < C::WT_N; nt++) {
                    v4f a0 = acc[mt][nt];
                    a0 = __builtin_amdgcn_mfma_f32_16x16x32_bf16(ah, bf[nt][0], a0, 0, 0, 0);
                    a0 = __builtin_amdgcn_mfma_f32_16x16x32_bf16(ah, bf[nt][1], a0, 0, 0, 0);
                    a0 = __builtin_amdgcn_mfma_f32_16x16x32_bf16(am, bf[nt][0], a0, 0, 0, 0);
                    a0 = __builtin_amdgcn_mfma_f32_16x16x32_bf16(am, bf[nt][1], a0, 0, 0, 0);
                    a0 = __builtin_amdgcn_mfma_f32_16x16x32_bf16(ah, bf[nt][2], a0, 0, 0, 0);
                    a0 = __builtin_amdgcn_mfma_f32_16x16x32_bf16(al, bf[nt][0], a0, 0, 0, 0);
                    acc[mt][nt] = a0;
                }
            }
        }
    }
    // ---- epilogue: C/D layout col=lane&15 (oc), row=(lane>>4)*4+reg (x) ----
#pragma unroll
    for (int mt = 0; mt < C::WT_M; mt++) {
        int x0 = (mbase + mt) * 16 + (lane >> 4) * 4;
#pragma unroll
        for (int nt = 0; nt < C::WT_N; nt++) {
            int oc = (nbase + nt) * 16 + (lane & 15);
            float bv = bias[oc];
            float v0 = acc[mt][nt][0] + bv;
            float v1 = acc[mt][nt][1] + bv;
            float v2 = acc[mt][nt][2] + bv;
            float v3 = acc[mt][nt][3] + bv;
            if constexpr (C::RELU_OUT) {
                v0 = fmaxf(v0, 0.f); v1 = fmaxf(v1, 0.f);
                v2 = fmaxf(v2, 0.f); v3 = fmaxf(v3, 0.f);
            }
            float4 o = make_float4(v0, v1, v2, v3);
            *(float4*)&out[(((n0 + n_img) * C::OC + oc) * 64 + oy) * 64 + x0] = o;
        }
    }
}

// ----- conv1: [8,1,256,256] -> [8,64,128,128], 4x4 s2 p1, relu (fp32) -------
__global__ __launch_bounds__(256) void conv1_k(
    const float* __restrict__ x, const float* __restrict__ w,
    const float* __restrict__ b, float* __restrict__ out)
{
    int tid = blockIdx.x * 256 + threadIdx.x;     // 131072 = 8*128*128
    int n   = tid >> 14;
    int rem = tid & 16383;
    int oy  = rem >> 7;
    int ox  = rem & 127;
    int iy0 = oy * 2 - 1, ix0 = ox * 2 - 1;
    const float* xb = x + n * 65536;
    float v[16];
#pragma unroll
    for (int ky = 0; ky < 4; ky++) {
#pragma unroll
        for (int kx = 0; kx < 4; kx++) {
            int iy = iy0 + ky, ix = ix0 + kx;
            bool ok = (iy >= 0) & (iy < 256) & (ix >= 0) & (ix < 256);
            v[ky * 4 + kx] = ok ? xb[iy * 256 + ix] : 0.f;
        }
    }
    int obase = (n * 64) * 16384 + (oy << 7) + ox;
    for (int oc = 0; oc < 64; oc++) {
        float acc = b[oc];
        const float* wp = w + oc * 16;
#pragma unroll
        for (int k = 0; k < 16; k++) acc = fmaf(v[k], wp[k], acc);
        out[obase + oc * 16384] = fmaxf(acc, 0.f);
    }
}

// ----- residual 1x1: h += conv1x1(relu(t)) + bias (fp32, proven) ------------
__global__ __launch_bounds__(256) void res1x1_k(
    const float* __restrict__ t, const float* __restrict__ w,
    const float* __restrict__ b, float* __restrict__ h)
{
    int tid = blockIdx.x * 256 + threadIdx.x;     // 65536
    int n   = tid >> 12;
    int pos = tid & 4095;
    int ocb = blockIdx.y * 32;
    const float* tb = t + n * 32 * 4096 + pos;
    float v[32];
#pragma unroll
    for (int ic = 0; ic < 32; ic++) v[ic] = fmaxf(tb[ic * 4096], 0.f);
    float* hb = h + (n * 128 + ocb) * 4096 + pos;
#pragma unroll
    for (int j = 0; j < 32; j++) {
        float acc = b[ocb + j];
        const float* wj = w + (ocb + j) * 32;
#pragma unroll
        for (int ic = 0; ic < 32; ic++) acc = fmaf(v[ic], wj[ic], acc);
        hb[j * 4096] += acc;
    }
}

// ----- fused 1x1 projection + cosine VQ (fp32, proven) ----------------------
__global__ __launch_bounds__(256) void prevq_k(
    const float* __restrict__ h, const float* __restrict__ wpre,
    const float* __restrict__ bpre, const float* __restrict__ cb,
    float* __restrict__ out)
{
    __shared__ float4 en[2048];
    for (int i = threadIdx.x; i < 2048; i += 256) {
        float c0 = cb[i * 4 + 0], c1 = cb[i * 4 + 1];
        float c2 = cb[i * 4 + 2], c3 = cb[i * 4 + 3];
        float nrm = sqrtf(c0 * c0 + c1 * c1 + c2 * c2 + c3 * c3) + 1e-12f;
        en[i] = make_float4(c0 / nrm, c1 / nrm, c2 / nrm, c3 / nrm);
    }
    __syncthreads();

    int tid = blockIdx.x * 256 + threadIdx.x;     // 65536
    int n   = tid >> 12;
    int pos = tid & 4095;
    const float* hb = h + n * 128 * 4096 + pos;
    float z0 = bpre[0], z1 = bpre[1], z2 = bpre[2], z3 = bpre[3];
    for (int ic = 0; ic < 128; ic++) {
        float v = fmaxf(hb[ic * 4096], 0.f);
        z0 = fmaf(v, wpre[ic],       z0);
        z1 = fmaf(v, wpre[128 + ic], z1);
        z2 = fmaf(v, wpre[256 + ic], z2);
        z3 = fmaf(v, wpre[384 + ic], z3);
    }
    float nrm = sqrtf(z0 * z0 + z1 * z1 + z2 * z2 + z3 * z3) + 1e-12f;
    z0 /= nrm; z1 /= nrm; z2 /= nrm; z3 /= nrm;

    float best = -1e30f;
    int   bidx = 0;
    for (int k = 0; k < 2048; k++) {
        float4 e = en[k];
        float s = z0 * e.x + z1 * e.y + z2 * e.z + z3 * e.w;
        if (s > best) { best = s; bidx = k; }     // strict > = first max
    }
    const float* q = cb + bidx * 4;
    out[(n * 4 + 0) * 4096 + pos] = q[0];
    out[(n * 4 + 1) * 4096 + pos] = q[1];
    out[(n * 4 + 2) * 4096 + pos] = q[2];
    out[(n * 4 + 3) * 4096 + pos] = q[3];
}

extern "C" void kernel_launch(void* const* d_in, const int* in_sizes, int n_in,
                              void* d_out, int out_size, void* d_ws, size_t ws_size,
                              hipStream_t stream)
{
    const float* x    = (const float*)d_in[0];
    const float* w1   = (const float*)d_in[1];
    const float* b1   = (const float*)d_in[2];
    const float* w2   = (const float*)d_in[3];
    const float* b2   = (const float*)d_in[4];
    const float* w3   = (const float*)d_in[5];
    const float* b3   = (const float*)d_in[6];
    const float* r1w1 = (const float*)d_in[7];
    const float* r1b1 = (const float*)d_in[8];
    const float* r1w2 = (const float*)d_in[9];
    const float* r1b2 = (const float*)d_in[10];
    const float* r2w1 = (const float*)d_in[11];
    const float* r2b1 = (const float*)d_in[12];
    const float* r2w2 = (const float*)d_in[13];
    const float* r2b2 = (const float*)d_in[14];
    const float* wpre = (const float*)d_in[15];
    const float* bpre = (const float*)d_in[16];
    const float* cb   = (const float*)d_in[17];
    float* out = (float*)d_out;

    float* ws   = (float*)d_ws;
    short* wsS  = (short*)d_ws;
    short* repW2 = wsS + W2_S;
    short* repW3 = wsS + W3_S;
    short* repR1 = wsS + WR1_S;
    short* repR2 = wsS + WR2_S;
    float* T = ws + T_OFF;
    float* B = ws + B_OFF;
    float* A = ws + A_OFF;

    // one-time weight repacks to MFMA limb layout
    repack_k<CfgConv2><<<512, 256, 0, stream>>>(w2,   repW2);
    repack_k<CfgConv3><<<576, 256, 0, stream>>>(w3,   repW3);
    repack_k<CfgRes>  <<<144, 256, 0, stream>>>(r1w1, repR1);
    repack_k<CfgRes>  <<<144, 256, 0, stream>>>(r2w1, repR2);

    // front end, batch split in halves ping-ponging through A
    conv1_k<<<512, 256, 0, stream>>>(x,               w1, b1, A);
    mfma_conv<CfgConv2><<<512, 256, 0, stream>>>(A, repW2, b2, B, 0);
    conv1_k<<<512, 256, 0, stream>>>(x + 8 * 65536,   w1, b1, A);
    mfma_conv<CfgConv2><<<512, 256, 0, stream>>>(A, repW2, b2, B, 8);

    // conv3: B -> h @ A
    mfma_conv<CfgConv3><<<1024, 256, 0, stream>>>(B, repW3, b3, A, 0);

    // residual block 1
    mfma_conv<CfgRes><<<1024, 256, 0, stream>>>(A, repR1, r1b1, T, 0);
    res1x1_k<<<dim3(256, 4), 256, 0, stream>>>(T, r1w2, r1b2, A);
    // residual block 2
    mfma_conv<CfgRes><<<1024, 256, 0, stream>>>(A, repR2, r2b1, T, 0);
    res1x1_k<<<dim3(256, 4), 256, 0, stream>>>(T, r2w2, r2b2, A);

    // 1x1 projection + vector quantization
    prevq_k<<<256, 256, 0, stream>>>(A, wpre, bpre, cb, out);
}

// Round 4
// 553.922 us; speedup vs baseline: 3.8883x; 1.4421x over previous
//
#include <hip/hip_runtime.h>
#include <math.h>

// ---------------------------------------------------------------------------
// ws layout (float offsets):
//   repW (shorts at base): repW2 @0(393216s), repW3 @393216(442368s),
//                          repR1 @835584(110592s), repR2 @946176(110592s)
//   T  @ 2097152  : t buffer [16,32,64,64]
//   B  @ 4194304  : conv2 out [16,128,64,64]
//   A  @ 12582912 : conv1 half-out [8,64,128,128] -> later h [16,128,64,64]
// B-weight repack layout (per-lane MFMA fragments, wave load = 1 KB contig):
//   dst[(((ct*3+L)*NTILE + nt)*512) + lane*8 + j], lane=(q*16+o), oc=nt*16+o,
//   ic = q*8+j   (B frag: n=lane&15 -> oc, k=quad*8+j -> ic)
// ---------------------------------------------------------------------------

typedef short v8s __attribute__((ext_vector_type(8)));
typedef float v4f __attribute__((ext_vector_type(4)));

#define T_OFF 2097152
#define B_OFF 4194304
#define A_OFF 12582912
#define W2_S 0
#define W3_S 393216
#define WR1_S 835584
#define WR2_S 946176

// 3-limb bf16 truncation decomposition: x = h+m+l + O(2^-24 |x|)
__device__ inline void limb3(float v, unsigned short& h, unsigned short& m,
                             unsigned short& l) {
    unsigned ub = __float_as_uint(v);
    unsigned hb = ub & 0xffff0000u;
    float r1 = v - __uint_as_float(hb);
    unsigned mb = __float_as_uint(r1) & 0xffff0000u;
    float r2 = r1 - __uint_as_float(mb);
    unsigned lb = __float_as_uint(r2) & 0xffff0000u;
    h = (unsigned short)(hb >> 16);
    m = (unsigned short)(mb >> 16);
    l = (unsigned short)(lb >> 16);
}

// ----- conv configs ---------------------------------------------------------
struct CfgConv2 {   // 4x4 s2 p1 as stride-1 conv over 4 phase planes
    static constexpr int NC = 8, NT = 4, OC = 128, ICG = 64, IN_H = 128, IN_W = 128;
    static constexpr bool RELU_IN = false, RELU_OUT = true;
    static constexpr int WT_M = 4, WT_N = 2;
    __device__ static void tap(int c, int t, int& ry, int& rx) {
        int py = (c >> 2) & 1, px = (c >> 1) & 1;
        ry = (t >> 1) - py; rx = (t & 1) - px;
    }
    __device__ static void inaddr(int c, int oy, int r, int X,
                                  int& Yg, int& Xg, int& ic0) {
        int py = (c >> 2) & 1, px = (c >> 1) & 1;
        Yg = 2 * (oy + r - 1) + py; Xg = 2 * X + px; ic0 = (c & 1) * 32;
    }
    __device__ static int widx(int c, int t, int oc, int ic) {
        int py = (c >> 2) & 1, px = (c >> 1) & 1, half = c & 1;
        int dy = 2 * (t >> 1) + (1 - py), dx = 2 * (t & 1) + (1 - px);
        return ((oc * 64 + half * 32 + ic) * 4 + dy) * 4 + dx;
    }
};
struct CfgConv3 {   // 3x3 s1 p1, 128->128
    static constexpr int NC = 4, NT = 9, OC = 128, ICG = 128, IN_H = 64, IN_W = 64;
    static constexpr bool RELU_IN = false, RELU_OUT = false;
    static constexpr int WT_M = 4, WT_N = 2;
    __device__ static void tap(int c, int t, int& ry, int& rx) {
        ry = t / 3 - 1; rx = t % 3 - 1;
    }
    __device__ static void inaddr(int c, int oy, int r, int X,
                                  int& Yg, int& Xg, int& ic0) {
        Yg = oy + r - 1; Xg = X; ic0 = c * 32;
    }
    __device__ static int widx(int c, int t, int oc, int ic) {
        return ((oc * 128 + c * 32 + ic) * 3 + t / 3) * 3 + t % 3;
    }
};
struct CfgRes {     // 3x3 s1 p1, relu(in), 128->32
    static constexpr int NC = 4, NT = 9, OC = 32, ICG = 128, IN_H = 64, IN_W = 64;
    static constexpr bool RELU_IN = true, RELU_OUT = false;
    static constexpr int WT_M = 1, WT_N = 2;
    __device__ static void tap(int c, int t, int& ry, int& rx) {
        ry = t / 3 - 1; rx = t % 3 - 1;
    }
    __device__ static void inaddr(int c, int oy, int r, int X,
                                  int& Yg, int& Xg, int& ic0) {
        Yg = oy + r - 1; Xg = X; ic0 = c * 32;
    }
    __device__ static int widx(int c, int t, int oc, int ic) {
        return ((oc * 128 + c * 32 + ic) * 3 + t / 3) * 3 + t % 3;
    }
};

// ----- weight repack: fp32 -> per-lane B-fragment limb layout ---------------
template <typename C>
__global__ __launch_bounds__(256) void repack_k(const float* __restrict__ w,
                                                short* __restrict__ dst) {
    int idx = blockIdx.x * 256 + threadIdx.x;
    int total = C::NC * C::NT * C::OC * 32;
    if (idx >= total) return;
    int s  = idx & 31;                    // ic within chunk
    int oc = (idx >> 5) % C::OC;
    int ct = idx / (32 * C::OC);
    int c = ct / C::NT, t = ct % C::NT;
    float val = w[C::widx(c, t, oc, s)];
    unsigned short h, m, l;
    limb3(val, h, m, l);
    constexpr int NTILE = C::OC / 16;
    int nt = oc >> 4, o = oc & 15, q = s >> 3, j = s & 7;
    int fr = ((q * 16 + o) << 3) + j;     // offset within 512-short tile
    dst[(((ct * 3 + 0) * NTILE + nt) << 9) + fr] = (short)h;
    dst[(((ct * 3 + 1) * NTILE + nt) << 9) + fr] = (short)m;
    dst[(((ct * 3 + 2) * NTILE + nt) << 9) + fr] = (short)l;
}

// ----- MFMA implicit-GEMM conv ----------------------------------------------
// block = (n_img, oy); M = 64 (x), N = OC. LDS holds ONLY the A-tile:
// 3 limb planes of [3 rows][66 cols][32 ic], 2-way-max bank swizzle.
// B fragments stream from global (L1-resident per tap).
template <typename C>
__global__ __launch_bounds__(256, 4) void mfma_conv(
    const float* __restrict__ in, const short* __restrict__ repw,
    const float* __restrict__ bias, float* __restrict__ out, int n0)
{
    constexpr int APLANE = 3 * 66 * 32;        // shorts (6336), dwords 3168
    constexpr int NTILE  = C::OC / 16;
    __shared__ __align__(16) short lA[3 * APLANE];

    int tid = threadIdx.x;
    int lane = tid & 63, wv = tid >> 6;
    int bx = blockIdx.x;
    int n_img = bx >> 6, oy = bx & 63;

    // zero halo cells (col 0 and 65, all rows, all limbs) — full cells,
    // swizzle-agnostic
    for (int idx = tid; idx < 3 * 3 * 2 * 16; idx += 256) {
        int plane = idx / 96;
        int rem = idx % 96;
        int rr = rem / 32;
        int hc = (rem / 16) & 1;
        int d = idx & 15;
        ((unsigned*)lA)[plane * 3168 + (rr * 66 + hc * 65) * 16 + d] = 0;
    }

    v4f acc[C::WT_M][C::WT_N] = {};
    int mbase = (C::WT_M == 4) ? 0 : wv;
    int nbase = (C::WT_M == 4) ? (wv * C::WT_N) : 0;

    int Xq = tid & 15, icp = tid >> 4;   // staging map: 16 cols x 16 ic-pairs
    int quad = lane >> 4;

    for (int c = 0; c < C::NC; c++) {
        __syncthreads();   // prev chunk's readers done before lA overwrite
        // ---- stage A chunk: 3 rows x 64 X x 32 ic, 3 limb planes ----
        for (int it = 0; it < 12; it++) {
            int r = it >> 2, xg = it & 3;
            int X = xg * 16 + Xq;
            int Yg, Xg, ic0;
            C::inaddr(c, oy, r, X, Yg, Xg, ic0);
            float v0 = 0.f, v1 = 0.f;
            if (Yg >= 0 && Yg < C::IN_H) {
                int gbase = ((n_img * C::ICG + ic0 + 2 * icp) * C::IN_H + Yg) * C::IN_W + Xg;
                v0 = in[gbase];
                v1 = in[gbase + C::IN_H * C::IN_W];
            }
            if constexpr (C::RELU_IN) { v0 = fmaxf(v0, 0.f); v1 = fmaxf(v1, 0.f); }
            unsigned short h0, m0, l0, h1, m1, l1;
            limb3(v0, h0, m0, l0);
            limb3(v1, h1, m1, l1);
            int cell = r * 66 + X + 1;
            int f = (cell + (cell >> 2)) & 3;              // bank-spread term
            int phys = (icp & 3) + 4 * (((icp >> 2) + f) & 3);
            unsigned* pa = (unsigned*)lA + cell * 16 + phys;
            pa[0]        = (unsigned)h0 | ((unsigned)h1 << 16);
            pa[3168]     = (unsigned)m0 | ((unsigned)m1 << 16);
            pa[2 * 3168] = (unsigned)l0 | ((unsigned)l1 << 16);
        }
        __syncthreads();   // lA staged before reads

        for (int t = 0; t < C::NT; t++) {
            int ry, rx;
            C::tap(c, t, ry, rx);
            // ---- B fragments direct from global (repacked per-lane) ----
            v8s bf[C::WT_N][3];
#pragma unroll
            for (int nt = 0; nt < C::WT_N; nt++) {
#pragma unroll
                for (int L = 0; L < 3; L++) {
                    const short* bp = repw +
                        ((((c * C::NT + t) * 3 + L) * NTILE + (nbase + nt)) << 9) +
                        (lane << 3);
                    bf[nt][L] = *(const v8s*)bp;
                }
            }
            // ---- A fragments from LDS ----
            v8s af[C::WT_M][3];
#pragma unroll
            for (int mt = 0; mt < C::WT_M; mt++) {
                int x = (mbase + mt) * 16 + (lane & 15);
                int cell = (ry + 1) * 66 + (x + rx + 1);
                int f = (cell + (cell >> 2)) & 3;
                int aa = cell * 32 + (((quad + f) & 3) << 3);
                af[mt][0] = *(const v8s*)&lA[aa];
                af[mt][1] = *(const v8s*)&lA[APLANE + aa];
                af[mt][2] = *(const v8s*)&lA[2 * APLANE + aa];
            }
#pragma unroll
            for (int mt = 0; mt < C::WT_M; mt++) {
#pragma unroll
                for (int nt = 0; nt < C::WT_N; nt++) {
                    v4f a0 = acc[mt][nt];
                    a0 = __builtin_amdgcn_mfma_f32_16x16x32_bf16(af[mt][0], bf[nt][0], a0, 0, 0, 0);
                    a0 = __builtin_amdgcn_mfma_f32_16x16x32_bf16(af[mt][0], bf[nt][1], a0, 0, 0, 0);
                    a0 = __builtin_amdgcn_mfma_f32_16x16x32_bf16(af[mt][1], bf[nt][0], a0, 0, 0, 0);
                    a0 = __builtin_amdgcn_mfma_f32_16x16x32_bf16(af[mt][1], bf[nt][1], a0, 0, 0, 0);
                    a0 = __builtin_amdgcn_mfma_f32_16x16x32_bf16(af[mt][0], bf[nt][2], a0, 0, 0, 0);
                    a0 = __builtin_amdgcn_mfma_f32_16x16x32_bf16(af[mt][2], bf[nt][0], a0, 0, 0, 0);
                    acc[mt][nt] = a0;
                }
            }
        }
    }
    // ---- epilogue: C/D layout col=lane&15 (oc), row=(lane>>4)*4+reg (x) ----
#pragma unroll
    for (int mt = 0; mt < C::WT_M; mt++) {
        int x0 = (mbase + mt) * 16 + (lane >> 4) * 4;
#pragma unroll
        for (int nt = 0; nt < C::WT_N; nt++) {
            int oc = (nbase + nt) * 16 + (lane & 15);
            float bv = bias[oc];
            float v0 = acc[mt][nt][0] + bv;
            float v1 = acc[mt][nt][1] + bv;
            float v2 = acc[mt][nt][2] + bv;
            float v3 = acc[mt][nt][3] + bv;
            if constexpr (C::RELU_OUT) {
                v0 = fmaxf(v0, 0.f); v1 = fmaxf(v1, 0.f);
                v2 = fmaxf(v2, 0.f); v3 = fmaxf(v3, 0.f);
            }
            float4 o = make_float4(v0, v1, v2, v3);
            *(float4*)&out[(((n0 + n_img) * C::OC + oc) * 64 + oy) * 64 + x0] = o;
        }
    }
}

// ----- conv1: [8,1,256,256] -> [8,64,128,128], 4x4 s2 p1, relu (fp32) -------
__global__ __launch_bounds__(256) void conv1_k(
    const float* __restrict__ x, const float* __restrict__ w,
    const float* __restrict__ b, float* __restrict__ out)
{
    int tid = blockIdx.x * 256 + threadIdx.x;     // 131072 = 8*128*128
    int n   = tid >> 14;
    int rem = tid & 16383;
    int oy  = rem >> 7;
    int ox  = rem & 127;
    int iy0 = oy * 2 - 1, ix0 = ox * 2 - 1;
    const float* xb = x + n * 65536;
    float v[16];
#pragma unroll
    for (int ky = 0; ky < 4; ky++) {
#pragma unroll
        for (int kx = 0; kx < 4; kx++) {
            int iy = iy0 + ky, ix = ix0 + kx;
            bool ok = (iy >= 0) & (iy < 256) & (ix >= 0) & (ix < 256);
            v[ky * 4 + kx] = ok ? xb[iy * 256 + ix] : 0.f;
        }
    }
    int obase = (n * 64) * 16384 + (oy << 7) + ox;
    for (int oc = 0; oc < 64; oc++) {
        float acc = b[oc];
        const float* wp = w + oc * 16;
#pragma unroll
        for (int k = 0; k < 16; k++) acc = fmaf(v[k], wp[k], acc);
        out[obase + oc * 16384] = fmaxf(acc, 0.f);
    }
}

// ----- residual 1x1: h += conv1x1(relu(t)) + bias (fp32, proven) ------------
__global__ __launch_bounds__(256) void res1x1_k(
    const float* __restrict__ t, const float* __restrict__ w,
    const float* __restrict__ b, float* __restrict__ h)
{
    int tid = blockIdx.x * 256 + threadIdx.x;     // 65536
    int n   = tid >> 12;
    int pos = tid & 4095;
    int ocb = blockIdx.y * 32;
    const float* tb = t + n * 32 * 4096 + pos;
    float v[32];
#pragma unroll
    for (int ic = 0; ic < 32; ic++) v[ic] = fmaxf(tb[ic * 4096], 0.f);
    float* hb = h + (n * 128 + ocb) * 4096 + pos;
#pragma unroll
    for (int j = 0; j < 32; j++) {
        float acc = b[ocb + j];
        const float* wj = w + (ocb + j) * 32;
#pragma unroll
        for (int ic = 0; ic < 32; ic++) acc = fmaf(v[ic], wj[ic], acc);
        hb[j * 4096] += acc;
    }
}

// ----- fused 1x1 projection + cosine VQ (fp32, proven) ----------------------
__global__ __launch_bounds__(256) void prevq_k(
    const float* __restrict__ h, const float* __restrict__ wpre,
    const float* __restrict__ bpre, const float* __restrict__ cb,
    float* __restrict__ out)
{
    __shared__ float4 en[2048];
    for (int i = threadIdx.x; i < 2048; i += 256) {
        float c0 = cb[i * 4 + 0], c1 = cb[i * 4 + 1];
        float c2 = cb[i * 4 + 2], c3 = cb[i * 4 + 3];
        float nrm = sqrtf(c0 * c0 + c1 * c1 + c2 * c2 + c3 * c3) + 1e-12f;
        en[i] = make_float4(c0 / nrm, c1 / nrm, c2 / nrm, c3 / nrm);
    }
    __syncthreads();

    int tid = blockIdx.x * 256 + threadIdx.x;     // 65536
    int n   = tid >> 12;
    int pos = tid & 4095;
    const float* hb = h + n * 128 * 4096 + pos;
    float z0 = bpre[0], z1 = bpre[1], z2 = bpre[2], z3 = bpre[3];
    for (int ic = 0; ic < 128; ic++) {
        float v = fmaxf(hb[ic * 4096], 0.f);
        z0 = fmaf(v, wpre[ic],       z0);
        z1 = fmaf(v, wpre[128 + ic], z1);
        z2 = fmaf(v, wpre[256 + ic], z2);
        z3 = fmaf(v, wpre[384 + ic], z3);
    }
    // argmax of cosine sim is invariant to positive scaling of z -> skip /||z||
    float best = -1e30f;
    int   bidx = 0;
    for (int k = 0; k < 2048; k++) {
        float4 e = en[k];
        float s = z0 * e.x + z1 * e.y + z2 * e.z + z3 * e.w;
        if (s > best) { best = s; bidx = k; }     // strict > = first max
    }
    const float* q = cb + bidx * 4;
    out[(n * 4 + 0) * 4096 + pos] = q[0];
    out[(n * 4 + 1) * 4096 + pos] = q[1];
    out[(n * 4 + 2) * 4096 + pos] = q[2];
    out[(n * 4 + 3) * 4096 + pos] = q[3];
}

extern "C" void kernel_launch(void* const* d_in, const int* in_sizes, int n_in,
                              void* d_out, int out_size, void* d_ws, size_t ws_size,
                              hipStream_t stream)
{
    const float* x    = (const float*)d_in[0];
    const float* w1   = (const float*)d_in[1];
    const float* b1   = (const float*)d_in[2];
    const float* w2   = (const float*)d_in[3];
    const float* b2   = (const float*)d_in[4];
    const float* w3   = (const float*)d_in[5];
    const float* b3   = (const float*)d_in[6];
    const float* r1w1 = (const float*)d_in[7];
    const float* r1b1 = (const float*)d_in[8];
    const float* r1w2 = (const float*)d_in[9];
    const float* r1b2 = (const float*)d_in[10];
    const float* r2w1 = (const float*)d_in[11];
    const float* r2b1 = (const float*)d_in[12];
    const float* r2w2 = (const float*)d_in[13];
    const float* r2b2 = (const float*)d_in[14];
    const float* wpre = (const float*)d_in[15];
    const float* bpre = (const float*)d_in[16];
    const float* cb   = (const float*)d_in[17];
    float* out = (float*)d_out;

    float* ws   = (float*)d_ws;
    short* wsS  = (short*)d_ws;
    short* repW2 = wsS + W2_S;
    short* repW3 = wsS + W3_S;
    short* repR1 = wsS + WR1_S;
    short* repR2 = wsS + WR2_S;
    float* T = ws + T_OFF;
    float* B = ws + B_OFF;
    float* A = ws + A_OFF;

    // one-time weight repacks to per-lane fragment limb layout
    repack_k<CfgConv2><<<512, 256, 0, stream>>>(w2,   repW2);
    repack_k<CfgConv3><<<576, 256, 0, stream>>>(w3,   repW3);
    repack_k<CfgRes>  <<<144, 256, 0, stream>>>(r1w1, repR1);
    repack_k<CfgRes>  <<<144, 256, 0, stream>>>(r2w1, repR2);

    // front end, batch split in halves ping-ponging through A
    conv1_k<<<512, 256, 0, stream>>>(x,               w1, b1, A);
    mfma_conv<CfgConv2><<<512, 256, 0, stream>>>(A, repW2, b2, B, 0);
    conv1_k<<<512, 256, 0, stream>>>(x + 8 * 65536,   w1, b1, A);
    mfma_conv<CfgConv2><<<512, 256, 0, stream>>>(A, repW2, b2, B, 8);

    // conv3: B -> h @ A
    mfma_conv<CfgConv3><<<1024, 256, 0, stream>>>(B, repW3, b3, A, 0);

    // residual block 1
    mfma_conv<CfgRes><<<1024, 256, 0, stream>>>(A, repR1, r1b1, T, 0);
    res1x1_k<<<dim3(256, 4), 256, 0, stream>>>(T, r1w2, r1b2, A);
    // residual block 2
    mfma_conv<CfgRes><<<1024, 256, 0, stream>>>(A, repR2, r2b1, T, 0);
    res1x1_k<<<dim3(256, 4), 256, 0, stream>>>(T, r2w2, r2b2, A);

    // 1x1 projection + vector quantization
    prevq_k<<<256, 256, 0, stream>>>(A, wpre, bpre, cb, out);
}

// Round 5
// 489.313 us; speedup vs baseline: 4.4017x; 1.1320x over previous
//
#include <hip/hip_runtime.h>
#include <math.h>

// ---------------------------------------------------------------------------
// ws layout:
//   shorts @0: repW2 393216, repW3 @393216 (442368), repR1 @835584 (110592),
//              repR2 @946176 (110592), repP1 @1056768 (12288), repP2 @1069056
//   floats:  B @4194304 : conv2 out / h' [16,128,64,64]
//            A @12582912: conv1 half-out [8,64,128,128] -> h [16,128,64,64]
// Flow: conv1->A, conv2 A->B (x2 halves); conv3 B->A; res1 A->B; res2 B->A;
//       prevq A->out.   (res ping-pongs to avoid halo races on h updates)
// ---------------------------------------------------------------------------

typedef short v8s __attribute__((ext_vector_type(8)));
typedef float v4f __attribute__((ext_vector_type(4)));

#define B_OFF 4194304
#define A_OFF 12582912
#define W2_S 0
#define W3_S 393216
#define WR1_S 835584
#define WR2_S 946176
#define WP1_S 1056768
#define WP2_S 1069056

// 3-limb bf16 truncation decomposition: x = h+m+l + O(2^-24 |x|)
__device__ inline void limb3(float v, unsigned short& h, unsigned short& m,
                             unsigned short& l) {
    unsigned ub = __float_as_uint(v);
    unsigned hb = ub & 0xffff0000u;
    float r1 = v - __uint_as_float(hb);
    unsigned mb = __float_as_uint(r1) & 0xffff0000u;
    float r2 = r1 - __uint_as_float(mb);
    unsigned lb = __float_as_uint(r2) & 0xffff0000u;
    h = (unsigned short)(hb >> 16);
    m = (unsigned short)(mb >> 16);
    l = (unsigned short)(lb >> 16);
}

// ----- conv configs ---------------------------------------------------------
struct CfgConv2 {   // 4x4 s2 p1 as stride-1 conv over 4 phase planes
    static constexpr int NC = 8, NT = 4, OC = 128, ICG = 64, IN_H = 128, IN_W = 128;
    static constexpr bool RELU_IN = false, RELU_OUT = true;
    __device__ static void tap(int c, int t, int& ry, int& rx) {
        int py = (c >> 2) & 1, px = (c >> 1) & 1;
        ry = (t >> 1) - py; rx = (t & 1) - px;
    }
    __device__ static void inaddr(int c, int oy, int r, int X,
                                  int& Yg, int& Xg, int& ic0) {
        int py = (c >> 2) & 1, px = (c >> 1) & 1;
        Yg = 2 * (oy + r - 1) + py; Xg = 2 * X + px; ic0 = (c & 1) * 32;
    }
    __device__ static int widx(int c, int t, int oc, int ic) {
        int py = (c >> 2) & 1, px = (c >> 1) & 1, half = c & 1;
        int dy = 2 * (t >> 1) + (1 - py), dx = 2 * (t & 1) + (1 - px);
        return ((oc * 64 + half * 32 + ic) * 4 + dy) * 4 + dx;
    }
};
struct CfgConv3 {   // 3x3 s1 p1, 128->128
    static constexpr int NC = 4, NT = 9, OC = 128, ICG = 128, IN_H = 64, IN_W = 64;
    static constexpr bool RELU_IN = false, RELU_OUT = false;
    __device__ static void tap(int c, int t, int& ry, int& rx) {
        ry = t / 3 - 1; rx = t % 3 - 1;
    }
    __device__ static void inaddr(int c, int oy, int r, int X,
                                  int& Yg, int& Xg, int& ic0) {
        Yg = oy + r - 1; Xg = X; ic0 = c * 32;
    }
    __device__ static int widx(int c, int t, int oc, int ic) {
        return ((oc * 128 + c * 32 + ic) * 3 + t / 3) * 3 + t % 3;
    }
};
struct CfgRes {     // 3x3 s1 p1, relu(in), 128->32
    static constexpr int NC = 4, NT = 9, OC = 32, ICG = 128, IN_H = 64, IN_W = 64;
    __device__ static int widx(int c, int t, int oc, int ic) {
        return ((oc * 128 + c * 32 + ic) * 3 + t / 3) * 3 + t % 3;
    }
};
struct Cfg1x1 {     // 1x1, 32->128
    static constexpr int NC = 1, NT = 1, OC = 128;
    __device__ static int widx(int c, int t, int oc, int ic) {
        return oc * 32 + ic;
    }
};

// ----- weight repack: fp32 -> per-lane B-fragment limb layout ---------------
// dst[(((ct*3+L)*NTILE + nt)<<9) + lane*8 + j], lane=q*16+o, oc=nt*16+o, ic=q*8+j
template <typename C>
__device__ inline void repack_one(const float* __restrict__ w,
                                  short* __restrict__ dst, int idx) {
    int s  = idx & 31;
    int oc = (idx >> 5) % C::OC;
    int ct = idx / (32 * C::OC);
    int c = ct / C::NT, t = ct % C::NT;
    float val = w[C::widx(c, t, oc, s)];
    unsigned short h, m, l;
    limb3(val, h, m, l);
    constexpr int NTILE = C::OC / 16;
    int nt = oc >> 4, o = oc & 15, q = s >> 3, j = s & 7;
    int fr = ((q * 16 + o) << 3) + j;
    dst[(((ct * 3 + 0) * NTILE + nt) << 9) + fr] = (short)h;
    dst[(((ct * 3 + 1) * NTILE + nt) << 9) + fr] = (short)m;
    dst[(((ct * 3 + 2) * NTILE + nt) << 9) + fr] = (short)l;
}

__global__ __launch_bounds__(256) void repack_all_k(
    const float* __restrict__ w2, const float* __restrict__ w3,
    const float* __restrict__ r1, const float* __restrict__ r2,
    const float* __restrict__ p1, const float* __restrict__ p2,
    short* __restrict__ base)
{
    int idx = blockIdx.x * 256 + threadIdx.x;
    if (idx < 131072) { repack_one<CfgConv2>(w2, base + W2_S, idx); return; }
    idx -= 131072;
    if (idx < 147456) { repack_one<CfgConv3>(w3, base + W3_S, idx); return; }
    idx -= 147456;
    if (idx < 36864)  { repack_one<CfgRes>(r1, base + WR1_S, idx); return; }
    idx -= 36864;
    if (idx < 36864)  { repack_one<CfgRes>(r2, base + WR2_S, idx); return; }
    idx -= 36864;
    if (idx < 4096)   { repack_one<Cfg1x1>(p1, base + WP1_S, idx); return; }
    idx -= 4096;
    if (idx < 4096)   { repack_one<Cfg1x1>(p2, base + WP2_S, idx); }
}

// ----- pipelined MFMA implicit-GEMM conv (WT_M=4, WT_N=2) -------------------
template <typename C>
__global__ __launch_bounds__(256, 3) void mfma_conv(
    const float* __restrict__ in, const short* __restrict__ repw,
    const float* __restrict__ bias, float* __restrict__ out, int n0)
{
    constexpr int APLANE = 3 * 66 * 32;        // shorts; dwords 3168
    constexpr int NTILE  = C::OC / 16;
    __shared__ __align__(16) short lA[3 * APLANE];

    int tid = threadIdx.x;
    int lane = tid & 63, wv = tid >> 6;
    int n_img = blockIdx.x >> 6, oy = blockIdx.x & 63;

    // zero halo cells (col 0 and 65, all rows, all limbs)
    for (int idx = tid; idx < 3 * 3 * 2 * 16; idx += 256) {
        int plane = idx / 96;
        int rem = idx % 96;
        int rr = rem / 32;
        int hc = (rem / 16) & 1;
        int d = idx & 15;
        ((unsigned*)lA)[plane * 3168 + (rr * 66 + hc * 65) * 16 + d] = 0;
    }

    v4f acc[4][2] = {};
    int nbase = wv * 2;
    int Xq = tid & 15, icp = tid >> 4, quad = lane >> 4;

    float pv[24];
    auto issue_loads = [&](int c) {
#pragma unroll
        for (int it = 0; it < 12; it++) {
            int r = it >> 2, xg = it & 3;
            int X = xg * 16 + Xq;
            int Yg, Xg, ic0;
            C::inaddr(c, oy, r, X, Yg, Xg, ic0);
            float v0 = 0.f, v1 = 0.f;
            if (Yg >= 0 && Yg < C::IN_H) {
                int g = ((n_img * C::ICG + ic0 + 2 * icp) * C::IN_H + Yg) * C::IN_W + Xg;
                v0 = in[g];
                v1 = in[g + C::IN_H * C::IN_W];
            }
            pv[2 * it] = v0; pv[2 * it + 1] = v1;
        }
    };
    auto load_bf = [&](int c, int t, v8s (&dst)[2][3]) {
#pragma unroll
        for (int nt = 0; nt < 2; nt++)
#pragma unroll
            for (int L = 0; L < 3; L++)
                dst[nt][L] = *(const v8s*)(repw +
                    ((((c * C::NT + t) * 3 + L) * NTILE + (nbase + nt)) << 9) +
                    (lane << 3));
    };

    issue_loads(0);

    for (int c = 0; c < C::NC; c++) {
        __syncthreads();   // prev chunk's readers done before lA overwrite
        // ---- consume pv -> lA limb planes ----
#pragma unroll
        for (int it = 0; it < 12; it++) {
            int r = it >> 2, xg = it & 3;
            int X = xg * 16 + Xq;
            float v0 = pv[2 * it], v1 = pv[2 * it + 1];
            if constexpr (C::RELU_IN) { v0 = fmaxf(v0, 0.f); v1 = fmaxf(v1, 0.f); }
            unsigned short h0, m0, l0, h1, m1, l1;
            limb3(v0, h0, m0, l0);
            limb3(v1, h1, m1, l1);
            int cell = r * 66 + X + 1;
            int f = (cell + (cell >> 2)) & 3;
            int phys = (icp & 3) + 4 * (((icp >> 2) + f) & 3);
            unsigned* pa = (unsigned*)lA + cell * 16 + phys;
            pa[0]        = (unsigned)h0 | ((unsigned)h1 << 16);
            pa[3168]     = (unsigned)m0 | ((unsigned)m1 << 16);
            pa[2 * 3168] = (unsigned)l0 | ((unsigned)l1 << 16);
        }
        __syncthreads();   // lA staged
        if (c + 1 < C::NC) issue_loads(c + 1);   // prefetch next chunk

        v8s bf[2][2][3];
        load_bf(c, 0, bf[0]);
#pragma unroll
        for (int t = 0; t < C::NT; t++) {
            constexpr int NTT = C::NT;
            if (t + 1 < NTT) load_bf(c, t + 1, bf[(t + 1) & 1]);
            int ry, rx;
            C::tap(c, t, ry, rx);
#pragma unroll
            for (int mt = 0; mt < 4; mt++) {
                int x = mt * 16 + (lane & 15);
                int cell = (ry + 1) * 66 + (x + rx + 1);
                int f = (cell + (cell >> 2)) & 3;
                int aa = cell * 32 + (((quad + f) & 3) << 3);
                v8s ah = *(const v8s*)&lA[aa];
                v8s am = *(const v8s*)&lA[APLANE + aa];
                v8s al = *(const v8s*)&lA[2 * APLANE + aa];
#pragma unroll
                for (int nt = 0; nt < 2; nt++) {
                    v4f a0 = acc[mt][nt];
                    a0 = __builtin_amdgcn_mfma_f32_16x16x32_bf16(ah, bf[t & 1][nt][0], a0, 0, 0, 0);
                    a0 = __builtin_amdgcn_mfma_f32_16x16x32_bf16(ah, bf[t & 1][nt][1], a0, 0, 0, 0);
                    a0 = __builtin_amdgcn_mfma_f32_16x16x32_bf16(am, bf[t & 1][nt][0], a0, 0, 0, 0);
                    a0 = __builtin_amdgcn_mfma_f32_16x16x32_bf16(am, bf[t & 1][nt][1], a0, 0, 0, 0);
                    a0 = __builtin_amdgcn_mfma_f32_16x16x32_bf16(ah, bf[t & 1][nt][2], a0, 0, 0, 0);
                    a0 = __builtin_amdgcn_mfma_f32_16x16x32_bf16(al, bf[t & 1][nt][0], a0, 0, 0, 0);
                    acc[mt][nt] = a0;
                }
            }
        }
    }
    // ---- epilogue: C/D layout col=lane&15 (oc), row=quad*4+reg (x) ----
#pragma unroll
    for (int mt = 0; mt < 4; mt++) {
        int x0 = mt * 16 + quad * 4;
#pragma unroll
        for (int nt = 0; nt < 2; nt++) {
            int oc = (nbase + nt) * 16 + (lane & 15);
            float bv = bias[oc];
            float v0 = acc[mt][nt][0] + bv;
            float v1 = acc[mt][nt][1] + bv;
            float v2 = acc[mt][nt][2] + bv;
            float v3 = acc[mt][nt][3] + bv;
            if constexpr (C::RELU_OUT) {
                v0 = fmaxf(v0, 0.f); v1 = fmaxf(v1, 0.f);
                v2 = fmaxf(v2, 0.f); v3 = fmaxf(v3, 0.f);
            }
            float4 o = make_float4(v0, v1, v2, v3);
            *(float4*)&out[(((n0 + n_img) * C::OC + oc) * 64 + oy) * 64 + x0] = o;
        }
    }
}

// ----- fused residual block ------------------------------------------------
// t = conv3x3(relu(h)) + b1 (128->32);  out = h + conv1x1(relu(t)) + b2
// block = (n, oy). Stage 1: limb-MFMA conv (wave wv owns mt=wv, nt=0..1).
// Stage 2: relu(t) limbs -> LDS (A-frag layout), 64x128x32 limb-GEMM.
__global__ __launch_bounds__(256, 4) void mfma_res(
    const float* __restrict__ in, const short* __restrict__ repw,
    const float* __restrict__ b1, const short* __restrict__ repp,
    const float* __restrict__ b2, float* __restrict__ out)
{
    constexpr int APLANE = 3 * 66 * 32;
    __shared__ __align__(16) short lA[3 * APLANE];

    int tid = threadIdx.x;
    int lane = tid & 63, wv = tid >> 6;
    int n_img = blockIdx.x >> 6, oy = blockIdx.x & 63;

    for (int idx = tid; idx < 3 * 3 * 2 * 16; idx += 256) {
        int plane = idx / 96;
        int rem = idx % 96;
        int rr = rem / 32;
        int hc = (rem / 16) & 1;
        int d = idx & 15;
        ((unsigned*)lA)[plane * 3168 + (rr * 66 + hc * 65) * 16 + d] = 0;
    }

    v4f acc[2] = {};
    int Xq = tid & 15, icp = tid >> 4, quad = lane >> 4;

    float pv[24];
    auto issue_loads = [&](int c) {
#pragma unroll
        for (int it = 0; it < 12; it++) {
            int r = it >> 2, xg = it & 3;
            int X = xg * 16 + Xq;
            int Yg = oy + r - 1;
            float v0 = 0.f, v1 = 0.f;
            if (Yg >= 0 && Yg < 64) {
                int g = ((n_img * 128 + c * 32 + 2 * icp) * 64 + Yg) * 64 + X;
                v0 = in[g];
                v1 = in[g + 4096];
            }
            pv[2 * it] = v0; pv[2 * it + 1] = v1;
        }
    };

    issue_loads(0);

    for (int c = 0; c < 4; c++) {
        __syncthreads();
#pragma unroll
        for (int it = 0; it < 12; it++) {
            int r = it >> 2, xg = it & 3;
            int X = xg * 16 + Xq;
            float v0 = fmaxf(pv[2 * it], 0.f);       // relu(h)
            float v1 = fmaxf(pv[2 * it + 1], 0.f);
            unsigned short h0, m0, l0, h1, m1, l1;
            limb3(v0, h0, m0, l0);
            limb3(v1, h1, m1, l1);
            int cell = r * 66 + X + 1;
            int f = (cell + (cell >> 2)) & 3;
            int phys = (icp & 3) + 4 * (((icp >> 2) + f) & 3);
            unsigned* pa = (unsigned*)lA + cell * 16 + phys;
            pa[0]        = (unsigned)h0 | ((unsigned)h1 << 16);
            pa[3168]     = (unsigned)m0 | ((unsigned)m1 << 16);
            pa[2 * 3168] = (unsigned)l0 | ((unsigned)l1 << 16);
        }
        __syncthreads();
        if (c + 1 < 4) issue_loads(c + 1);

        v8s bf[2][2][3];
        auto load_bf = [&](int t, v8s (&dst)[2][3]) {
#pragma unroll
            for (int nt = 0; nt < 2; nt++)
#pragma unroll
                for (int L = 0; L < 3; L++)
                    dst[nt][L] = *(const v8s*)(repw +
                        ((((c * 9 + t) * 3 + L) * 2 + nt) << 9) + (lane << 3));
        };
        load_bf(0, bf[0]);
#pragma unroll
        for (int t = 0; t < 9; t++) {
            if (t + 1 < 9) load_bf(t + 1, bf[(t + 1) & 1]);
            int ry = t / 3 - 1, rx = t % 3 - 1;
            int x = wv * 16 + (lane & 15);
            int cell = (ry + 1) * 66 + (x + rx + 1);
            int f = (cell + (cell >> 2)) & 3;
            int aa = cell * 32 + (((quad + f) & 3) << 3);
            v8s ah = *(const v8s*)&lA[aa];
            v8s am = *(const v8s*)&lA[APLANE + aa];
            v8s al = *(const v8s*)&lA[2 * APLANE + aa];
#pragma unroll
            for (int nt = 0; nt < 2; nt++) {
                v4f a0 = acc[nt];
                a0 = __builtin_amdgcn_mfma_f32_16x16x32_bf16(ah, bf[t & 1][nt][0], a0, 0, 0, 0);
                a0 = __builtin_amdgcn_mfma_f32_16x16x32_bf16(ah, bf[t & 1][nt][1], a0, 0, 0, 0);
                a0 = __builtin_amdgcn_mfma_f32_16x16x32_bf16(am, bf[t & 1][nt][0], a0, 0, 0, 0);
                a0 = __builtin_amdgcn_mfma_f32_16x16x32_bf16(am, bf[t & 1][nt][1], a0, 0, 0, 0);
                a0 = __builtin_amdgcn_mfma_f32_16x16x32_bf16(ah, bf[t & 1][nt][2], a0, 0, 0, 0);
                a0 = __builtin_amdgcn_mfma_f32_16x16x32_bf16(al, bf[t & 1][nt][0], a0, 0, 0, 0);
                acc[nt] = a0;
            }
        }
    }

    // ===== stage 2: relu(t+b1) limbs -> LDS (A-frag layout, cell=x) =====
    __syncthreads();   // all lA tap-readers done; reuse front of lA
#pragma unroll
    for (int nt = 0; nt < 2; nt++) {
        int ic = nt * 16 + (lane & 15);     // t-channel = GEMM-2 k index
        int icp2 = ic >> 1, hilo = ic & 1;
        float bv = b1[ic];
#pragma unroll
        for (int r = 0; r < 4; r++) {
            int x = wv * 16 + quad * 4 + r;
            float v = fmaxf(acc[nt][r] + bv, 0.f);
            unsigned short h, m, l;
            limb3(v, h, m, l);
            int f = (x + (x >> 2)) & 3;
            int phys = (icp2 & 3) + 4 * (((icp2 >> 2) + f) & 3);
            int sa = x * 32 + phys * 2 + hilo;
            lA[sa] = (short)h;
            lA[2048 + sa] = (short)m;
            lA[4096 + sa] = (short)l;
        }
    }
    __syncthreads();

    // GEMM-2: M=64 (x, mt=wv), N=128 (oc2, nt=0..7), K=32
    v4f a2[8] = {};
    {
        int x = wv * 16 + (lane & 15);
        int f = (x + (x >> 2)) & 3;
        int aa = x * 32 + (((quad + f) & 3) << 3);
        v8s ah = *(const v8s*)&lA[aa];
        v8s am = *(const v8s*)&lA[2048 + aa];
        v8s al = *(const v8s*)&lA[4096 + aa];
#pragma unroll
        for (int nt = 0; nt < 8; nt++) {
            v8s bh = *(const v8s*)(repp + ((0 * 8 + nt) << 9) + (lane << 3));
            v8s bm = *(const v8s*)(repp + ((1 * 8 + nt) << 9) + (lane << 3));
            v8s bl = *(const v8s*)(repp + ((2 * 8 + nt) << 9) + (lane << 3));
            v4f a0 = a2[nt];
            a0 = __builtin_amdgcn_mfma_f32_16x16x32_bf16(ah, bh, a0, 0, 0, 0);
            a0 = __builtin_amdgcn_mfma_f32_16x16x32_bf16(ah, bm, a0, 0, 0, 0);
            a0 = __builtin_amdgcn_mfma_f32_16x16x32_bf16(am, bh, a0, 0, 0, 0);
            a0 = __builtin_amdgcn_mfma_f32_16x16x32_bf16(am, bm, a0, 0, 0, 0);
            a0 = __builtin_amdgcn_mfma_f32_16x16x32_bf16(ah, bl, a0, 0, 0, 0);
            a0 = __builtin_amdgcn_mfma_f32_16x16x32_bf16(al, bh, a0, 0, 0, 0);
            a2[nt] = a0;
        }
    }
    // epilogue: out = h + t2 + b2
#pragma unroll
    for (int nt = 0; nt < 8; nt++) {
        int oc = nt * 16 + (lane & 15);
        int x0 = wv * 16 + quad * 4;
        int off = ((n_img * 128 + oc) * 64 + oy) * 64 + x0;
        float4 hv = *(const float4*)&in[off];
        float bv = b2[oc];
        float4 o = make_float4(hv.x + a2[nt][0] + bv, hv.y + a2[nt][1] + bv,
                               hv.z + a2[nt][2] + bv, hv.w + a2[nt][3] + bv);
        *(float4*)&out[off] = o;
    }
}

// ----- conv1: [8,1,256,256] -> [8,64,128,128], 4x4 s2 p1, relu (fp32) -------
__global__ __launch_bounds__(256) void conv1_k(
    const float* __restrict__ x, const float* __restrict__ w,
    const float* __restrict__ b, float* __restrict__ out)
{
    int tid = blockIdx.x * 256 + threadIdx.x;     // 131072
    int n   = tid >> 14;
    int rem = tid & 16383;
    int oy  = rem >> 7;
    int ox  = rem & 127;
    int iy0 = oy * 2 - 1, ix0 = ox * 2 - 1;
    const float* xb = x + n * 65536;
    float v[16];
#pragma unroll
    for (int ky = 0; ky < 4; ky++) {
#pragma unroll
        for (int kx = 0; kx < 4; kx++) {
            int iy = iy0 + ky, ix = ix0 + kx;
            bool ok = (iy >= 0) & (iy < 256) & (ix >= 0) & (ix < 256);
            v[ky * 4 + kx] = ok ? xb[iy * 256 + ix] : 0.f;
        }
    }
    int obase = (n * 64) * 16384 + (oy << 7) + ox;
    for (int oc = 0; oc < 64; oc++) {
        float acc = b[oc];
        const float* wp = w + oc * 16;
#pragma unroll
        for (int k = 0; k < 16; k++) acc = fmaf(v[k], wp[k], acc);
        out[obase + oc * 16384] = fmaxf(acc, 0.f);
    }
}

// ----- fused 1x1 projection + cosine VQ (fp32, proven) ----------------------
__global__ __launch_bounds__(256) void prevq_k(
    const float* __restrict__ h, const float* __restrict__ wpre,
    const float* __restrict__ bpre, const float* __restrict__ cb,
    float* __restrict__ out)
{
    __shared__ float4 en[2048];
    for (int i = threadIdx.x; i < 2048; i += 256) {
        float c0 = cb[i * 4 + 0], c1 = cb[i * 4 + 1];
        float c2 = cb[i * 4 + 2], c3 = cb[i * 4 + 3];
        float nrm = sqrtf(c0 * c0 + c1 * c1 + c2 * c2 + c3 * c3) + 1e-12f;
        en[i] = make_float4(c0 / nrm, c1 / nrm, c2 / nrm, c3 / nrm);
    }
    __syncthreads();

    int tid = blockIdx.x * 256 + threadIdx.x;     // 65536
    int n   = tid >> 12;
    int pos = tid & 4095;
    const float* hb = h + n * 128 * 4096 + pos;
    float z0 = bpre[0], z1 = bpre[1], z2 = bpre[2], z3 = bpre[3];
    for (int ic = 0; ic < 128; ic++) {
        float v = fmaxf(hb[ic * 4096], 0.f);
        z0 = fmaf(v, wpre[ic],       z0);
        z1 = fmaf(v, wpre[128 + ic], z1);
        z2 = fmaf(v, wpre[256 + ic], z2);
        z3 = fmaf(v, wpre[384 + ic], z3);
    }
    // argmax of cosine sim is invariant to positive scaling of z
    float best = -1e30f;
    int   bidx = 0;
    for (int k = 0; k < 2048; k++) {
        float4 e = en[k];
        float s = z0 * e.x + z1 * e.y + z2 * e.z + z3 * e.w;
        if (s > best) { best = s; bidx = k; }     // strict > = first max
    }
    const float* q = cb + bidx * 4;
    out[(n * 4 + 0) * 4096 + pos] = q[0];
    out[(n * 4 + 1) * 4096 + pos] = q[1];
    out[(n * 4 + 2) * 4096 + pos] = q[2];
    out[(n * 4 + 3) * 4096 + pos] = q[3];
}

extern "C" void kernel_launch(void* const* d_in, const int* in_sizes, int n_in,
                              void* d_out, int out_size, void* d_ws, size_t ws_size,
                              hipStream_t stream)
{
    const float* x    = (const float*)d_in[0];
    const float* w1   = (const float*)d_in[1];
    const float* b1   = (const float*)d_in[2];
    const float* w2   = (const float*)d_in[3];
    const float* b2   = (const float*)d_in[4];
    const float* w3   = (const float*)d_in[5];
    const float* b3   = (const float*)d_in[6];
    const float* r1w1 = (const float*)d_in[7];
    const float* r1b1 = (const float*)d_in[8];
    const float* r1w2 = (const float*)d_in[9];
    const float* r1b2 = (const float*)d_in[10];
    const float* r2w1 = (const float*)d_in[11];
    const float* r2b1 = (const float*)d_in[12];
    const float* r2w2 = (const float*)d_in[13];
    const float* r2b2 = (const float*)d_in[14];
    const float* wpre = (const float*)d_in[15];
    const float* bpre = (const float*)d_in[16];
    const float* cb   = (const float*)d_in[17];
    float* out = (float*)d_out;

    float* ws   = (float*)d_ws;
    short* wsS  = (short*)d_ws;
    float* B = ws + B_OFF;
    float* A = ws + A_OFF;

    // one merged repack for all 6 weight tensors
    repack_all_k<<<1408, 256, 0, stream>>>(w2, w3, r1w1, r2w1, r1w2, r2w2, wsS);

    // front end, batch split in halves ping-ponging through A
    conv1_k<<<512, 256, 0, stream>>>(x,               w1, b1, A);
    mfma_conv<CfgConv2><<<512, 256, 0, stream>>>(A, wsS + W2_S, b2, B, 0);
    conv1_k<<<512, 256, 0, stream>>>(x + 8 * 65536,   w1, b1, A);
    mfma_conv<CfgConv2><<<512, 256, 0, stream>>>(A, wsS + W2_S, b2, B, 8);

    // conv3: B -> h @ A
    mfma_conv<CfgConv3><<<1024, 256, 0, stream>>>(B, wsS + W3_S, b3, A, 0);

    // fused residual blocks (ping-pong A->B->A)
    mfma_res<<<1024, 256, 0, stream>>>(A, wsS + WR1_S, r1b1, wsS + WP1_S, r1b2, B);
    mfma_res<<<1024, 256, 0, stream>>>(B, wsS + WR2_S, r2b1, wsS + WP2_S, r2b2, A);

    // 1x1 projection + vector quantization
    prevq_k<<<256, 256, 0, stream>>>(A, wpre, bpre, cb, out);
}